// Round 1
// baseline (1731.874 us; speedup 1.0000x reference)
//
#include <hip/hip_runtime.h>

#define IMGS 64
#define HH 512
#define WW 512
#define NPIX (HH * WW)          // 262144 pixels per image
#define STEPS 10

// ---------------------------------------------------------------------------
// kbound: out = (x - y)^2 elementwise (float4 vectorized), plus block 0
// initializes all per-step per-image accumulators (min=+inf, max=0, sum=0).
// ---------------------------------------------------------------------------
__global__ __launch_bounds__(256) void kbound(const float* __restrict__ x,
                                              const float* __restrict__ y,
                                              float* __restrict__ out,
                                              unsigned int* __restrict__ accMin,
                                              unsigned int* __restrict__ accMax,
                                              double* __restrict__ accSum) {
    if (blockIdx.x == 0) {
        for (int i = threadIdx.x; i < STEPS * IMGS; i += blockDim.x) {
            accMin[i] = 0x7f800000u;  // +inf
            accMax[i] = 0u;           // +0.0f  (ero >= 0 always)
            accSum[i] = 0.0;
        }
    }
    const int n4 = IMGS * NPIX / 4;
    const float4* x4 = (const float4*)x;
    const float4* y4 = (const float4*)y;
    float4* o4 = (float4*)out;
    for (int i = blockIdx.x * blockDim.x + threadIdx.x; i < n4;
         i += gridDim.x * blockDim.x) {
        float4 a = x4[i];
        float4 b = y4[i];
        float4 r;
        r.x = (a.x - b.x) * (a.x - b.x);
        r.y = (a.y - b.y) * (a.y - b.y);
        r.z = (a.z - b.z) * (a.z - b.z);
        r.w = (a.w - b.w) * (a.w - b.w);
        o4[i] = r;
    }
}

// ---------------------------------------------------------------------------
// kconv: one erosion step.
//   - reads raw previous field, applies per-image affine normalization on the
//     fly (scale=1/ptp, off=mn*scale) for in-bounds taps (OOB taps are exact 0,
//     matching zero-padding of the *normalized* field in the reference)
//   - dil = 0.2*(C + N + S + E + W), ero = max(dil - 0.5, 0)
//   - writes raw ero; block-reduces min/max/sum -> device atomics per image
// Grid: IMGS * 256 blocks, 256 threads, 4 pixels (one float4) per thread.
// ---------------------------------------------------------------------------
__global__ __launch_bounds__(256) void kconv(const float* __restrict__ src,
                                             float* __restrict__ dst,
                                             const unsigned int* __restrict__ pMin,
                                             const unsigned int* __restrict__ pMax,
                                             unsigned int* __restrict__ oMin,
                                             unsigned int* __restrict__ oMax,
                                             double* __restrict__ oSum,
                                             int useNorm) {
    const int img = blockIdx.x >> 8;                       // 256 blocks/image
    const int t = ((blockIdx.x & 255) << 8) | threadIdx.x; // vec4 idx [0,65536)
    const int row = t >> 7;                                // t / 128
    const int vcol = t & 127;                              // float4 column
    const float* im = src + (size_t)img * NPIX;
    const float4* imv = (const float4*)im;

    float scale = 1.0f, off = 0.0f;
    if (useNorm) {
        float mn = __uint_as_float(pMin[img]);
        float ptp = __uint_as_float(pMax[img]) - mn;
        if (ptp > 0.0f) { scale = 1.0f / ptp; off = mn * scale; }
    }

    float4 c = imv[t];
    float4 u = make_float4(0.f, 0.f, 0.f, 0.f);
    float4 d = make_float4(0.f, 0.f, 0.f, 0.f);
    float lf = 0.f, rt = 0.f;

    c.x = fmaf(c.x, scale, -off);
    c.y = fmaf(c.y, scale, -off);
    c.z = fmaf(c.z, scale, -off);
    c.w = fmaf(c.w, scale, -off);
    if (row > 0) {
        u = imv[t - 128];
        u.x = fmaf(u.x, scale, -off);
        u.y = fmaf(u.y, scale, -off);
        u.z = fmaf(u.z, scale, -off);
        u.w = fmaf(u.w, scale, -off);
    }
    if (row < HH - 1) {
        d = imv[t + 128];
        d.x = fmaf(d.x, scale, -off);
        d.y = fmaf(d.y, scale, -off);
        d.z = fmaf(d.z, scale, -off);
        d.w = fmaf(d.w, scale, -off);
    }
    if (vcol > 0)       lf = fmaf(im[(t << 2) - 1], scale, -off);
    if (vcol < 127)     rt = fmaf(im[(t << 2) + 4], scale, -off);

    float4 e;
    e.x = 0.2f * (u.x + d.x + lf  + c.x + c.y);
    e.y = 0.2f * (u.y + d.y + c.x + c.y + c.z);
    e.z = 0.2f * (u.z + d.z + c.y + c.z + c.w);
    e.w = 0.2f * (u.w + d.w + c.z + c.w + rt);
    e.x = fmaxf(e.x - 0.5f, 0.0f);
    e.y = fmaxf(e.y - 0.5f, 0.0f);
    e.z = fmaxf(e.z - 0.5f, 0.0f);
    e.w = fmaxf(e.w - 0.5f, 0.0f);

    ((float4*)(dst + (size_t)img * NPIX))[t] = e;

    float tmin = fminf(fminf(e.x, e.y), fminf(e.z, e.w));
    float tmax = fmaxf(fmaxf(e.x, e.y), fmaxf(e.z, e.w));
    float tsum = (e.x + e.y) + (e.z + e.w);

    #pragma unroll
    for (int o2 = 32; o2 > 0; o2 >>= 1) {
        tmin = fminf(tmin, __shfl_down(tmin, o2));
        tmax = fmaxf(tmax, __shfl_down(tmax, o2));
        tsum += __shfl_down(tsum, o2);
    }

    __shared__ float smin[4], smax[4], ssum[4];
    const int wave = threadIdx.x >> 6;
    const int lane = threadIdx.x & 63;
    if (lane == 0) { smin[wave] = tmin; smax[wave] = tmax; ssum[wave] = tsum; }
    __syncthreads();
    if (threadIdx.x == 0) {
        float m0 = fminf(fminf(smin[0], smin[1]), fminf(smin[2], smin[3]));
        float m1 = fmaxf(fmaxf(smax[0], smax[1]), fmaxf(smax[2], smax[3]));
        float s  = (ssum[0] + ssum[1]) + (ssum[2] + ssum[3]);
        atomicMin(&oMin[img], __float_as_uint(m0));
        atomicMax(&oMax[img], __float_as_uint(m1));
        atomicAdd(&oSum[img], (double)s);
    }
}

// ---------------------------------------------------------------------------
// kfinal: per image i, per step k: sum of normalized ero = (S - N*mn)/ptp
// (or S if ptp == 0), weighted by (k+1)^2; mean over everything -> out[0].
// One wave of 64 threads (one per image).
// ---------------------------------------------------------------------------
__global__ void kfinal(const unsigned int* __restrict__ accMin,
                       const unsigned int* __restrict__ accMax,
                       const double* __restrict__ accSum,
                       float* __restrict__ out) {
    const int i = threadIdx.x;  // image index, 64 threads
    double total = 0.0;
    for (int k = 0; k < STEPS; ++k) {
        float mn = __uint_as_float(accMin[k * IMGS + i]);
        float mx = __uint_as_float(accMax[k * IMGS + i]);
        float ptp = mx - mn;
        double S = accSum[k * IMGS + i];
        double sn = (ptp > 0.0f)
                        ? (S - (double)NPIX * (double)mn) / (double)ptp
                        : S;
        total += sn * (double)((k + 1) * (k + 1));
    }
    #pragma unroll
    for (int o2 = 32; o2 > 0; o2 >>= 1) total += __shfl_down(total, o2);
    if (i == 0) out[0] = (float)(total / ((double)IMGS * (double)NPIX));
}

// ---------------------------------------------------------------------------
extern "C" void kernel_launch(void* const* d_in, const int* in_sizes, int n_in,
                              void* d_out, int out_size, void* d_ws, size_t ws_size,
                              hipStream_t stream) {
    const float* x = (const float*)d_in[0];
    const float* y = (const float*)d_in[1];
    float* out = (float*)d_out;

    char* ws = (char*)d_ws;
    const size_t bufBytes = (size_t)IMGS * NPIX * sizeof(float);  // 64 MiB
    float* bufA = (float*)ws;
    float* bufB = (float*)(ws + bufBytes);
    char* accBase = ws + 2 * bufBytes;
    unsigned int* accMin = (unsigned int*)accBase;          // STEPS*IMGS
    unsigned int* accMax = accMin + STEPS * IMGS;           // STEPS*IMGS
    double* accSum = (double*)(accMax + STEPS * IMGS);      // STEPS*IMGS

    kbound<<<2048, 256, 0, stream>>>(x, y, bufA, accMin, accMax, accSum);

    float* cur = bufA;
    float* nxt = bufB;
    for (int k = 0; k < STEPS; ++k) {
        const unsigned int* pMin = (k > 0) ? accMin + (k - 1) * IMGS : nullptr;
        const unsigned int* pMax = (k > 0) ? accMax + (k - 1) * IMGS : nullptr;
        kconv<<<IMGS * 256, 256, 0, stream>>>(cur, nxt, pMin, pMax,
                                              accMin + k * IMGS,
                                              accMax + k * IMGS,
                                              accSum + k * IMGS,
                                              (k > 0) ? 1 : 0);
        float* tmp = cur; cur = nxt; nxt = tmp;
    }

    kfinal<<<1, 64, 0, stream>>>(accMin, accMax, accSum, out);
}

// Round 4
// 1665.119 us; speedup vs baseline: 1.0401x; 1.0401x over previous
//
#include <hip/hip_runtime.h>

#define IMGS 64
#define HH 512
#define WW 512
#define NPIX (HH * WW)          // 262144 pixels per image
#define STEPS 10
#define BLKS_PER_IMG 256        // 256 blocks x 256 threads x 4 px = 262144

// ---------------------------------------------------------------------------
// kinit: per-step per-image min/max accumulators. min=+inf, max=+0.
// ---------------------------------------------------------------------------
__global__ void kinit(unsigned int* __restrict__ accMin,
                      unsigned int* __restrict__ accMax) {
    for (int i = threadIdx.x; i < STEPS * IMGS; i += blockDim.x) {
        accMin[i] = 0x7f800000u;  // +inf
        accMax[i] = 0u;           // +0.0f (ero >= 0 always)
    }
}

// ---------------------------------------------------------------------------
// kconv<FIRST>: one erosion step.
//   FIRST: source field is (x-y)^2 computed on the fly (no norm).
//   else : source is previous raw ero, normalized on the fly via per-image
//          affine (scale=1/ptp, off=mn*scale); OOB taps are exact 0, matching
//          zero-padding of the *normalized* field in the reference.
//   dil = 0.2*(C+N+S+E+W); ero = max(dil-0.5, 0); write raw ero.
//   Block-reduce min/max -> native uint atomics; block sum -> plain f32 store
//   (NO f64 atomic - that was a CAS-loop serializer).
// ---------------------------------------------------------------------------
template <int FIRST>
__global__ __launch_bounds__(256) void kconv(const float* __restrict__ xg,
                                             const float* __restrict__ yg,
                                             const float* __restrict__ src,
                                             float* __restrict__ dst,
                                             const unsigned int* __restrict__ pMin,
                                             const unsigned int* __restrict__ pMax,
                                             unsigned int* __restrict__ oMin,
                                             unsigned int* __restrict__ oMax,
                                             float* __restrict__ oSum) {
    const int img = blockIdx.x >> 8;
    const int blk = blockIdx.x & 255;
    const int t = (blk << 8) | threadIdx.x;   // vec4 index [0, 65536)
    const int row = t >> 7;
    const int vcol = t & 127;
    const size_t base = (size_t)img * NPIX;

    float scale = 1.0f, off = 0.0f;
    if (!FIRST) {
        float mn = __uint_as_float(pMin[img]);
        float ptp = __uint_as_float(pMax[img]) - mn;
        if (ptp > 0.0f) { scale = 1.0f / ptp; off = mn * scale; }
    }

    auto ld4 = [&](int j) -> float4 {
        if (FIRST) {
            float4 a = ((const float4*)(xg + base))[j];
            float4 b = ((const float4*)(yg + base))[j];
            float4 r;
            r.x = (a.x - b.x) * (a.x - b.x);
            r.y = (a.y - b.y) * (a.y - b.y);
            r.z = (a.z - b.z) * (a.z - b.z);
            r.w = (a.w - b.w) * (a.w - b.w);
            return r;
        } else {
            float4 v = ((const float4*)(src + base))[j];
            v.x = fmaf(v.x, scale, -off);
            v.y = fmaf(v.y, scale, -off);
            v.z = fmaf(v.z, scale, -off);
            v.w = fmaf(v.w, scale, -off);
            return v;
        }
    };
    auto ld1 = [&](int p) -> float {
        if (FIRST) {
            float d = xg[base + p] - yg[base + p];
            return d * d;
        } else {
            return fmaf(src[base + p], scale, -off);
        }
    };

    float4 c = ld4(t);
    float4 u = make_float4(0.f, 0.f, 0.f, 0.f);
    float4 d = make_float4(0.f, 0.f, 0.f, 0.f);
    float lf = 0.f, rt = 0.f;
    if (row > 0)       u = ld4(t - 128);
    if (row < HH - 1)  d = ld4(t + 128);
    if (vcol > 0)      lf = ld1((t << 2) - 1);
    if (vcol < 127)    rt = ld1((t << 2) + 4);

    float4 e;
    e.x = 0.2f * (u.x + d.x + lf  + c.x + c.y);
    e.y = 0.2f * (u.y + d.y + c.x + c.y + c.z);
    e.z = 0.2f * (u.z + d.z + c.y + c.z + c.w);
    e.w = 0.2f * (u.w + d.w + c.z + c.w + rt);
    e.x = fmaxf(e.x - 0.5f, 0.0f);
    e.y = fmaxf(e.y - 0.5f, 0.0f);
    e.z = fmaxf(e.z - 0.5f, 0.0f);
    e.w = fmaxf(e.w - 0.5f, 0.0f);

    ((float4*)(dst + base))[t] = e;

    float tmin = fminf(fminf(e.x, e.y), fminf(e.z, e.w));
    float tmax = fmaxf(fmaxf(e.x, e.y), fmaxf(e.z, e.w));
    float tsum = (e.x + e.y) + (e.z + e.w);

    #pragma unroll
    for (int o2 = 32; o2 > 0; o2 >>= 1) {
        tmin = fminf(tmin, __shfl_down(tmin, o2));
        tmax = fmaxf(tmax, __shfl_down(tmax, o2));
        tsum += __shfl_down(tsum, o2);
    }

    __shared__ float smin[4], smax[4], ssum[4];
    const int wave = threadIdx.x >> 6;
    const int lane = threadIdx.x & 63;
    if (lane == 0) { smin[wave] = tmin; smax[wave] = tmax; ssum[wave] = tsum; }
    __syncthreads();
    if (threadIdx.x == 0) {
        float m0 = fminf(fminf(smin[0], smin[1]), fminf(smin[2], smin[3]));
        float m1 = fmaxf(fmaxf(smax[0], smax[1]), fmaxf(smax[2], smax[3]));
        float s  = (ssum[0] + ssum[1]) + (ssum[2] + ssum[3]);
        atomicMin(&oMin[img], __float_as_uint(m0));
        atomicMax(&oMax[img], __float_as_uint(m1));
        oSum[img * BLKS_PER_IMG + blk] = s;   // plain store, reduced in kfinal1
    }
}

// ---------------------------------------------------------------------------
// kfinal1: one block per image. For each step k, reduce the 256 f32 block
// partials in f64, apply sum-of-normalized = (S - N*mn)/ptp (or S if ptp==0),
// weight by (k+1)^2, accumulate. Writes per-image double total.
// ---------------------------------------------------------------------------
__global__ __launch_bounds__(256) void kfinal1(const unsigned int* __restrict__ accMin,
                                               const unsigned int* __restrict__ accMax,
                                               const float* __restrict__ sums,
                                               double* __restrict__ perImg) {
    const int img = blockIdx.x;
    const int wave = threadIdx.x >> 6;
    const int lane = threadIdx.x & 63;
    __shared__ double sh[4];
    double tot = 0.0;
    for (int k = 0; k < STEPS; ++k) {
        double v = (double)sums[(k * IMGS + img) * BLKS_PER_IMG + threadIdx.x];
        #pragma unroll
        for (int o2 = 32; o2 > 0; o2 >>= 1) v += __shfl_down(v, o2);
        if (lane == 0) sh[wave] = v;
        __syncthreads();
        if (threadIdx.x == 0) {
            double S = (sh[0] + sh[1]) + (sh[2] + sh[3]);
            float mn = __uint_as_float(accMin[k * IMGS + img]);
            float mx = __uint_as_float(accMax[k * IMGS + img]);
            float ptp = mx - mn;
            double sn = (ptp > 0.0f)
                            ? (S - (double)NPIX * (double)mn) / (double)ptp
                            : S;
            tot += sn * (double)((k + 1) * (k + 1));
        }
        __syncthreads();
    }
    if (threadIdx.x == 0) perImg[img] = tot;
}

// ---------------------------------------------------------------------------
// kfinal2: sum 64 per-image doubles, divide, write scalar.
// ---------------------------------------------------------------------------
__global__ void kfinal2(const double* __restrict__ perImg,
                        float* __restrict__ out) {
    double v = perImg[threadIdx.x];
    #pragma unroll
    for (int o2 = 32; o2 > 0; o2 >>= 1) v += __shfl_down(v, o2);
    if (threadIdx.x == 0)
        out[0] = (float)(v / ((double)IMGS * (double)NPIX));
}

// ---------------------------------------------------------------------------
extern "C" void kernel_launch(void* const* d_in, const int* in_sizes, int n_in,
                              void* d_out, int out_size, void* d_ws, size_t ws_size,
                              hipStream_t stream) {
    const float* x = (const float*)d_in[0];
    const float* y = (const float*)d_in[1];
    float* out = (float*)d_out;

    char* ws = (char*)d_ws;
    const size_t bufBytes = (size_t)IMGS * NPIX * sizeof(float);  // 64 MiB
    float* bufA = (float*)ws;
    float* bufB = (float*)(ws + bufBytes);
    char* p = ws + 2 * bufBytes;
    unsigned int* accMin = (unsigned int*)p;             p += STEPS * IMGS * 4;
    unsigned int* accMax = (unsigned int*)p;             p += STEPS * IMGS * 4;
    float* sums = (float*)p;                             p += STEPS * IMGS * BLKS_PER_IMG * 4;
    double* perImg = (double*)p;

    kinit<<<1, 256, 0, stream>>>(accMin, accMax);

    float* cur = bufA;   // step-0 writes into bufA
    float* nxt = bufB;
    // step 0: sources x,y directly
    kconv<1><<<IMGS * BLKS_PER_IMG, 256, 0, stream>>>(
        x, y, nullptr, bufA, nullptr, nullptr,
        accMin + 0, accMax + 0, sums + 0);
    for (int k = 1; k < STEPS; ++k) {
        kconv<0><<<IMGS * BLKS_PER_IMG, 256, 0, stream>>>(
            nullptr, nullptr, cur, nxt,
            accMin + (k - 1) * IMGS, accMax + (k - 1) * IMGS,
            accMin + k * IMGS, accMax + k * IMGS,
            sums + (size_t)k * IMGS * BLKS_PER_IMG);
        float* tmp = cur; cur = nxt; nxt = tmp;
    }

    kfinal1<<<IMGS, 256, 0, stream>>>(accMin, accMax, sums, perImg);
    kfinal2<<<1, 64, 0, stream>>>(perImg, out);
}

// Round 9
// 338.951 us; speedup vs baseline: 5.1095x; 4.9126x over previous
//
#include <hip/hip_runtime.h>

#define IMGS 64
#define HH 512
#define WW 512
#define NPIX (HH * WW)          // 262144 pixels per image
#define STEPS 10
#define BLKS_PER_IMG 256        // 256 blocks x 256 threads x 4 px = 262144
#define WPI 1024                // wave partials per image (256 blocks x 4 waves)

// ---------------------------------------------------------------------------
// kconv<FIRST>: one erosion step. NO LDS, NO __syncthreads, NO atomics.
//   FIRST: source = (x-y)^2 on the fly; else source = prev ero normalized on
//   the fly (per-image affine; OOB taps exact 0 = zero-pad of normalized field).
//   dil = 0.2*(C+N+S+E+W); ero = max(dil-0.5,0); write raw ero.
//   Each wave shfl-reduces min/max/sum of its 256 px; lane 0 stores one
//   float4 partial. Horizontal neighbors come from __shfl of already-loaded
//   data (waves never cross rows: 64 vec4/wave, 128 vec4/row); only lanes
//   0/63 issue an edge scalar load.
// ---------------------------------------------------------------------------
template <int FIRST>
__global__ __launch_bounds__(256) void kconv(const float* __restrict__ xg,
                                             const float* __restrict__ yg,
                                             const float* __restrict__ src,
                                             float* __restrict__ dst,
                                             const float* __restrict__ pMin,
                                             const float* __restrict__ pMax,
                                             float4* __restrict__ part) {
    const int img = blockIdx.x >> 8;
    const int blk = blockIdx.x & 255;
    const int tid = threadIdx.x;
    const int t = (blk << 8) | tid;      // vec4 index in image [0, 65536)
    const int row = t >> 7;              // 128 vec4 per row
    const int vcol = t & 127;
    const int lane = tid & 63;
    const size_t base = (size_t)img * NPIX;

    float scale = 1.0f, off = 0.0f;
    if (!FIRST) {
        float mn = pMin[img];
        float ptp = pMax[img] - mn;
        if (ptp > 0.0f) { scale = 1.0f / ptp; off = mn * scale; }
    }

    auto ld4 = [&](int j) -> float4 {
        if (FIRST) {
            float4 a = ((const float4*)(xg + base))[j];
            float4 b = ((const float4*)(yg + base))[j];
            float4 r;
            r.x = (a.x - b.x) * (a.x - b.x);
            r.y = (a.y - b.y) * (a.y - b.y);
            r.z = (a.z - b.z) * (a.z - b.z);
            r.w = (a.w - b.w) * (a.w - b.w);
            return r;
        } else {
            float4 v = ((const float4*)(src + base))[j];
            v.x = fmaf(v.x, scale, -off);
            v.y = fmaf(v.y, scale, -off);
            v.z = fmaf(v.z, scale, -off);
            v.w = fmaf(v.w, scale, -off);
            return v;
        }
    };
    auto ld1 = [&](int p) -> float {
        if (FIRST) {
            float d = xg[base + p] - yg[base + p];
            return d * d;
        } else {
            return fmaf(src[base + p], scale, -off);
        }
    };

    float4 c = ld4(t);
    float4 u = (row > 0)      ? ld4(t - 128) : make_float4(0.f, 0.f, 0.f, 0.f);
    float4 d = (row < HH - 1) ? ld4(t + 128) : make_float4(0.f, 0.f, 0.f, 0.f);

    // horizontal neighbors via cross-lane shuffle of already-normalized data
    float lf = __shfl_up(c.w, 1);        // lane l gets lane l-1's c.w
    float rt = __shfl_down(c.x, 1);      // lane l gets lane l+1's c.x
    if (lane == 0)  lf = (vcol > 0)   ? ld1((t << 2) - 1) : 0.0f;
    if (lane == 63) rt = (vcol < 127) ? ld1((t << 2) + 4) : 0.0f;

    float4 e;
    e.x = 0.2f * (u.x + d.x + lf  + c.x + c.y);
    e.y = 0.2f * (u.y + d.y + c.x + c.y + c.z);
    e.z = 0.2f * (u.z + d.z + c.y + c.z + c.w);
    e.w = 0.2f * (u.w + d.w + c.z + c.w + rt);
    e.x = fmaxf(e.x - 0.5f, 0.0f);
    e.y = fmaxf(e.y - 0.5f, 0.0f);
    e.z = fmaxf(e.z - 0.5f, 0.0f);
    e.w = fmaxf(e.w - 0.5f, 0.0f);

    ((float4*)(dst + base))[t] = e;

    float tmin = fminf(fminf(e.x, e.y), fminf(e.z, e.w));
    float tmax = fmaxf(fmaxf(e.x, e.y), fmaxf(e.z, e.w));
    float tsum = (e.x + e.y) + (e.z + e.w);

    #pragma unroll
    for (int o2 = 32; o2 > 0; o2 >>= 1) {
        tmin = fminf(tmin, __shfl_down(tmin, o2));
        tmax = fmaxf(tmax, __shfl_down(tmax, o2));
        tsum += __shfl_down(tsum, o2);
    }

    if (lane == 0) {
        int widx = (blk << 2) | (tid >> 6);         // [0, 1024)
        part[img * WPI + widx] = make_float4(tmin, tmax, tsum, 0.0f);
    }
}

// ---------------------------------------------------------------------------
// kred: one block per image; reduce the 1024 wave partials of this step to
// per-(step,image) min / max (f32) and sum (f64). Plain stores, no atomics.
// ---------------------------------------------------------------------------
__global__ __launch_bounds__(256) void kred(const float4* __restrict__ part,
                                            float* __restrict__ oMin,
                                            float* __restrict__ oMax,
                                            double* __restrict__ oSum) {
    const int img = blockIdx.x;
    const int tid = threadIdx.x;
    const int wave = tid >> 6;
    const int lane = tid & 63;

    float tmin = __uint_as_float(0x7f800000u);
    float tmax = 0.0f;
    double tsum = 0.0;
    #pragma unroll
    for (int i = 0; i < 4; ++i) {
        float4 p = part[img * WPI + tid * 4 + i];
        tmin = fminf(tmin, p.x);
        tmax = fmaxf(tmax, p.y);
        tsum += (double)p.z;
    }
    #pragma unroll
    for (int o2 = 32; o2 > 0; o2 >>= 1) {
        tmin = fminf(tmin, __shfl_down(tmin, o2));
        tmax = fmaxf(tmax, __shfl_down(tmax, o2));
        tsum += __shfl_down(tsum, o2);
    }
    __shared__ float smin[4], smax[4];
    __shared__ double ssum[4];
    if (lane == 0) { smin[wave] = tmin; smax[wave] = tmax; ssum[wave] = tsum; }
    __syncthreads();
    if (tid == 0) {
        oMin[img] = fminf(fminf(smin[0], smin[1]), fminf(smin[2], smin[3]));
        oMax[img] = fmaxf(fmaxf(smax[0], smax[1]), fmaxf(smax[2], smax[3]));
        oSum[img] = (ssum[0] + ssum[1]) + (ssum[2] + ssum[3]);
    }
}

// ---------------------------------------------------------------------------
// kfinal: per image i, per step k: sum of normalized ero = (S - N*mn)/ptp
// (or S if ptp==0), weighted by (k+1)^2; mean over everything -> out[0].
// ---------------------------------------------------------------------------
__global__ void kfinal(const float* __restrict__ accMin,
                       const float* __restrict__ accMax,
                       const double* __restrict__ accSum,
                       float* __restrict__ out) {
    const int i = threadIdx.x;  // image index, 64 threads
    double tot = 0.0;
    for (int k = 0; k < STEPS; ++k) {
        float mn = accMin[k * IMGS + i];
        float ptp = accMax[k * IMGS + i] - mn;
        double S = accSum[k * IMGS + i];
        double sn = (ptp > 0.0f)
                        ? (S - (double)NPIX * (double)mn) / (double)ptp
                        : S;
        tot += sn * (double)((k + 1) * (k + 1));
    }
    #pragma unroll
    for (int o2 = 32; o2 > 0; o2 >>= 1) tot += __shfl_down(tot, o2);
    if (i == 0) out[0] = (float)(tot / ((double)IMGS * (double)NPIX));
}

// ---------------------------------------------------------------------------
extern "C" void kernel_launch(void* const* d_in, const int* in_sizes, int n_in,
                              void* d_out, int out_size, void* d_ws, size_t ws_size,
                              hipStream_t stream) {
    const float* x = (const float*)d_in[0];
    const float* y = (const float*)d_in[1];
    float* out = (float*)d_out;

    char* ws = (char*)d_ws;
    const size_t bufBytes = (size_t)IMGS * NPIX * sizeof(float);  // 64 MiB
    float* bufA = (float*)ws;
    float* bufB = (float*)(ws + bufBytes);
    float4* part = (float4*)(ws + 2 * bufBytes);           // IMGS*WPI*16B = 1 MiB
    float* accMin = (float*)(part + IMGS * WPI);           // STEPS*IMGS f32
    float* accMax = accMin + STEPS * IMGS;                 // STEPS*IMGS f32
    double* accSum = (double*)(accMax + STEPS * IMGS);     // STEPS*IMGS f64

    // step 0: sources x,y directly
    kconv<1><<<IMGS * BLKS_PER_IMG, 256, 0, stream>>>(
        x, y, nullptr, bufA, nullptr, nullptr, part);
    kred<<<IMGS, 256, 0, stream>>>(part, accMin, accMax, accSum);

    float* cur = bufA;
    float* nxt = bufB;
    for (int k = 1; k < STEPS; ++k) {
        kconv<0><<<IMGS * BLKS_PER_IMG, 256, 0, stream>>>(
            nullptr, nullptr, cur, nxt,
            accMin + (k - 1) * IMGS, accMax + (k - 1) * IMGS, part);
        kred<<<IMGS, 256, 0, stream>>>(part, accMin + k * IMGS,
                                       accMax + k * IMGS, accSum + k * IMGS);
        float* tmp = cur; cur = nxt; nxt = tmp;
    }

    kfinal<<<1, 64, 0, stream>>>(accMin, accMax, accSum, out);
}

// Round 10
// 269.766 us; speedup vs baseline: 6.4199x; 1.2565x over previous
//
#include <hip/hip_runtime.h>

#define IMGS 64
#define HH 512
#define WW 512
#define NPIX (HH * WW)          // 262144 pixels per image
#define STEPS 10
#define RSTRIP 8                // rows per wave strip
#define TILE_ROWS 16            // 2 strip-groups * RSTRIP
#define BLKS_PER_IMG 32         // 512 / 16
#define NBLK (IMGS * BLKS_PER_IMG)   // 2048
#define WPI 128                 // partials per image = 32 blocks * 4 waves

// ---------------------------------------------------------------------------
// kconv<FIRST>: one erosion step, register sliding-window stencil.
//   Block = 16 rows x 512. Each of 4 waves owns a half-row (64 vec4 cols) x 8
//   rows; rows slide through registers pm1/p0/p1 so each src row is fetched
//   once per strip (halo ratio 1.25x vs ~2x for 2-row blocks).
//   FIRST: source = (x-y)^2 on the fly; else prev ero normalized on the fly
//   (per-image affine; OOB taps exact 0 = zero-pad of the normalized field).
//   dil = 0.2*(C+N+S+E+W); ero = max(dil-0.5,0); write raw ero.
//   Per-wave min/max (f32) + sum (f64) partial, plain stores. No LDS/atomics.
//   XCD swizzle: contiguous work chunks per XCD for halo L2 locality.
// ---------------------------------------------------------------------------
template <int FIRST>
__global__ __launch_bounds__(256) void kconv(const float* __restrict__ xg,
                                             const float* __restrict__ yg,
                                             const float* __restrict__ src,
                                             float* __restrict__ dst,
                                             const float* __restrict__ pMin,
                                             const float* __restrict__ pMax,
                                             float2* __restrict__ pmm,
                                             double* __restrict__ psum) {
    const int bid = blockIdx.x;
    const int swz = (bid & 7) * (NBLK / 8) + (bid >> 3);  // XCD-contiguous
    const int img = swz >> 5;             // 32 blocks per image
    const int blk = swz & 31;
    const int tid = threadIdx.x;
    const int w = tid >> 6;
    const int lane = tid & 63;
    const int h = w & 1;                  // half-row (0: cols 0-63, 1: 64-127)
    const int g = w >> 1;                 // strip group (0: rows +0-7, 1: +8-15)
    const int vc = h * 64 + lane;         // vec4 column [0,128)
    const int ys = blk * TILE_ROWS + g * RSTRIP;
    const size_t base = (size_t)img * NPIX;

    float scale = 1.0f, off = 0.0f;
    if (!FIRST) {
        float mn = pMin[img];
        float ptp = pMax[img] - mn;
        if (ptp > 0.0f) { scale = 1.0f / ptp; off = mn * scale; }
    }

    const float4* xv = (const float4*)(xg + base);
    const float4* yv = (const float4*)(yg + base);
    const float4* sv = (const float4*)(src + base);

    auto ld4 = [&](int r) -> float4 {     // row r, this thread's vec4 column
        if (FIRST) {
            float4 a = xv[r * 128 + vc];
            float4 b = yv[r * 128 + vc];
            float4 v;
            v.x = (a.x - b.x) * (a.x - b.x);
            v.y = (a.y - b.y) * (a.y - b.y);
            v.z = (a.z - b.z) * (a.z - b.z);
            v.w = (a.w - b.w) * (a.w - b.w);
            return v;
        } else {
            float4 v = sv[r * 128 + vc];
            v.x = fmaf(v.x, scale, -off);
            v.y = fmaf(v.y, scale, -off);
            v.z = fmaf(v.z, scale, -off);
            v.w = fmaf(v.w, scale, -off);
            return v;
        }
    };
    auto ld1 = [&](int r, int pcol) -> float {
        if (FIRST) {
            float d = xg[base + r * WW + pcol] - yg[base + r * WW + pcol];
            return d * d;
        } else {
            return fmaf(src[base + r * WW + pcol], scale, -off);
        }
    };

    const float4 z4 = make_float4(0.f, 0.f, 0.f, 0.f);
    float4 pm1 = (ys > 0) ? ld4(ys - 1) : z4;
    float4 p0 = ld4(ys);

    float tmin = __uint_as_float(0x7f800000u);
    float tmax = 0.0f;
    float tsum = 0.0f;
    float4* dv = (float4*)(dst + base);

    #pragma unroll
    for (int i = 0; i < RSTRIP; ++i) {
        const int y = ys + i;
        float4 p1 = (y + 1 < HH) ? ld4(y + 1) : z4;

        float lf = __shfl_up(p0.w, 1);
        float rt = __shfl_down(p0.x, 1);
        if (lane == 0)  lf = (vc > 0)   ? ld1(y, vc * 4 - 1) : 0.0f;
        if (lane == 63) rt = (vc < 127) ? ld1(y, vc * 4 + 4) : 0.0f;

        float4 e;
        e.x = 0.2f * (pm1.x + p1.x + lf   + p0.x + p0.y);
        e.y = 0.2f * (pm1.y + p1.y + p0.x + p0.y + p0.z);
        e.z = 0.2f * (pm1.z + p1.z + p0.y + p0.z + p0.w);
        e.w = 0.2f * (pm1.w + p1.w + p0.z + p0.w + rt);
        e.x = fmaxf(e.x - 0.5f, 0.0f);
        e.y = fmaxf(e.y - 0.5f, 0.0f);
        e.z = fmaxf(e.z - 0.5f, 0.0f);
        e.w = fmaxf(e.w - 0.5f, 0.0f);

        dv[y * 128 + vc] = e;

        tmin = fminf(tmin, fminf(fminf(e.x, e.y), fminf(e.z, e.w)));
        tmax = fmaxf(tmax, fmaxf(fmaxf(e.x, e.y), fmaxf(e.z, e.w)));
        tsum += (e.x + e.y) + (e.z + e.w);

        pm1 = p0;
        p0 = p1;
    }

    double dsum = (double)tsum;
    #pragma unroll
    for (int o2 = 32; o2 > 0; o2 >>= 1) {
        tmin = fminf(tmin, __shfl_down(tmin, o2));
        tmax = fmaxf(tmax, __shfl_down(tmax, o2));
        dsum += __shfl_down(dsum, o2);
    }

    if (lane == 0) {
        const int idx = img * WPI + blk * 4 + w;
        pmm[idx] = make_float2(tmin, tmax);
        psum[idx] = dsum;
    }
}

// ---------------------------------------------------------------------------
// kred: one block per image; reduce 128 wave partials to per-(step,image)
// min / max (f32) and sum (f64). Plain stores.
// ---------------------------------------------------------------------------
__global__ __launch_bounds__(128) void kred(const float2* __restrict__ pmm,
                                            const double* __restrict__ psum,
                                            float* __restrict__ oMin,
                                            float* __restrict__ oMax,
                                            double* __restrict__ oSum) {
    const int img = blockIdx.x;
    const int tid = threadIdx.x;
    const int w = tid >> 6;
    const int lane = tid & 63;

    float2 mm = pmm[img * WPI + tid];
    double s = psum[img * WPI + tid];
    float tmin = mm.x, tmax = mm.y;

    #pragma unroll
    for (int o2 = 32; o2 > 0; o2 >>= 1) {
        tmin = fminf(tmin, __shfl_down(tmin, o2));
        tmax = fmaxf(tmax, __shfl_down(tmax, o2));
        s += __shfl_down(s, o2);
    }
    __shared__ float smin[2], smax[2];
    __shared__ double ssum[2];
    if (lane == 0) { smin[w] = tmin; smax[w] = tmax; ssum[w] = s; }
    __syncthreads();
    if (tid == 0) {
        oMin[img] = fminf(smin[0], smin[1]);
        oMax[img] = fmaxf(smax[0], smax[1]);
        oSum[img] = ssum[0] + ssum[1];
    }
}

// ---------------------------------------------------------------------------
// kfinal: per image i, per step k: sum of normalized ero = (S - N*mn)/ptp
// (or S if ptp==0), weighted by (k+1)^2; mean over everything -> out[0].
// ---------------------------------------------------------------------------
__global__ void kfinal(const float* __restrict__ accMin,
                       const float* __restrict__ accMax,
                       const double* __restrict__ accSum,
                       float* __restrict__ out) {
    const int i = threadIdx.x;  // image index, 64 threads
    double tot = 0.0;
    for (int k = 0; k < STEPS; ++k) {
        float mn = accMin[k * IMGS + i];
        float ptp = accMax[k * IMGS + i] - mn;
        double S = accSum[k * IMGS + i];
        double sn = (ptp > 0.0f)
                        ? (S - (double)NPIX * (double)mn) / (double)ptp
                        : S;
        tot += sn * (double)((k + 1) * (k + 1));
    }
    #pragma unroll
    for (int o2 = 32; o2 > 0; o2 >>= 1) tot += __shfl_down(tot, o2);
    if (i == 0) out[0] = (float)(tot / ((double)IMGS * (double)NPIX));
}

// ---------------------------------------------------------------------------
extern "C" void kernel_launch(void* const* d_in, const int* in_sizes, int n_in,
                              void* d_out, int out_size, void* d_ws, size_t ws_size,
                              hipStream_t stream) {
    const float* x = (const float*)d_in[0];
    const float* y = (const float*)d_in[1];
    float* out = (float*)d_out;

    char* ws = (char*)d_ws;
    const size_t bufBytes = (size_t)IMGS * NPIX * sizeof(float);  // 64 MiB
    float* bufA = (float*)ws;
    float* bufB = (float*)(ws + bufBytes);
    char* p = ws + 2 * bufBytes;
    float2* pmm = (float2*)p;                 p += IMGS * WPI * sizeof(float2);
    double* psum = (double*)p;                p += IMGS * WPI * sizeof(double);
    float* accMin = (float*)p;                p += STEPS * IMGS * sizeof(float);
    float* accMax = (float*)p;                p += STEPS * IMGS * sizeof(float);
    double* accSum = (double*)p;

    // step 0: sources x,y directly
    kconv<1><<<NBLK, 256, 0, stream>>>(x, y, nullptr, bufA,
                                       nullptr, nullptr, pmm, psum);
    kred<<<IMGS, 128, 0, stream>>>(pmm, psum, accMin, accMax, accSum);

    float* cur = bufA;
    float* nxt = bufB;
    for (int k = 1; k < STEPS; ++k) {
        kconv<0><<<NBLK, 256, 0, stream>>>(
            nullptr, nullptr, cur, nxt,
            accMin + (k - 1) * IMGS, accMax + (k - 1) * IMGS, pmm, psum);
        kred<<<IMGS, 128, 0, stream>>>(pmm, psum, accMin + k * IMGS,
                                       accMax + k * IMGS, accSum + k * IMGS);
        float* tmp = cur; cur = nxt; nxt = tmp;
    }

    kfinal<<<1, 64, 0, stream>>>(accMin, accMax, accSum, out);
}

// Round 11
// 251.605 us; speedup vs baseline: 6.8833x; 1.0722x over previous
//
#include <hip/hip_runtime.h>

#define IMGS 64
#define HH 512
#define WW 512
#define NPIX (HH * WW)          // 262144 pixels per image
#define STEPS 10
#define RSTRIP 8                // rows per wave strip
#define TILE_ROWS 16            // 2 strip-groups * RSTRIP
#define BLKS_PER_IMG 32         // 512 / 16
#define NBLK (IMGS * BLKS_PER_IMG)   // 2048
#define WPI 128                 // partials per image per step (32 blk * 4 waves)

// ---------------------------------------------------------------------------
// kconv<FIRST,STORE>: one erosion step, register sliding-window stencil,
// with the previous step's min/max reduction FUSED at block start.
//   - prev stats: each wave butterfly-reduces (shfl_xor, no LDS/barrier) the
//     128 float2 partials of step k-1 (1 KB broadcast, L2-hit) -> scale/off.
//   - FIRST: source = (x-y)^2 on the fly; else prev ero normalized on the fly
//     (per-image affine; OOB taps exact 0 = zero-pad of the normalized field).
//   - dil = 0.2*(C+N+S+E+W); ero = max(dil-0.5,0).
//   - STORE=0 (last step): skip the 64 MB field write; only partials stored.
//   - per-wave min/max (f32) + sum (f64) partials, plain stores. No atomics.
//   - XCD swizzle: contiguous work chunks per XCD for halo L2 locality.
// ---------------------------------------------------------------------------
template <int FIRST, int STORE>
__global__ __launch_bounds__(256) void kconv(const float* __restrict__ xg,
                                             const float* __restrict__ yg,
                                             const float* __restrict__ src,
                                             float* __restrict__ dst,
                                             const float2* __restrict__ prevMM,
                                             float2* __restrict__ pmm,
                                             double* __restrict__ psum) {
    const int bid = blockIdx.x;
    const int swz = (bid & 7) * (NBLK / 8) + (bid >> 3);  // XCD-contiguous
    const int img = swz >> 5;             // 32 blocks per image
    const int blk = swz & 31;
    const int tid = threadIdx.x;
    const int w = tid >> 6;
    const int lane = tid & 63;
    const int h = w & 1;                  // half-row (0: cols 0-63, 1: 64-127)
    const int g = w >> 1;                 // strip group (0: rows +0-7, 1: +8-15)
    const int vc = h * 64 + lane;         // vec4 column [0,128)
    const int ys = blk * TILE_ROWS + g * RSTRIP;
    const size_t base = (size_t)img * NPIX;

    float scale = 1.0f, off = 0.0f;
    if (!FIRST) {
        float2 a = prevMM[img * WPI + lane];
        float2 b = prevMM[img * WPI + 64 + lane];
        float tmn = fminf(a.x, b.x);
        float tmx = fmaxf(a.y, b.y);
        #pragma unroll
        for (int o2 = 32; o2 > 0; o2 >>= 1) {
            tmn = fminf(tmn, __shfl_xor(tmn, o2));
            tmx = fmaxf(tmx, __shfl_xor(tmx, o2));
        }
        float ptp = tmx - tmn;
        if (ptp > 0.0f) { scale = 1.0f / ptp; off = tmn * scale; }
    }

    const float4* xv = (const float4*)(xg + base);
    const float4* yv = (const float4*)(yg + base);
    const float4* sv = (const float4*)(src + base);

    auto ld4 = [&](int r) -> float4 {     // row r, this thread's vec4 column
        if (FIRST) {
            float4 a = xv[r * 128 + vc];
            float4 b = yv[r * 128 + vc];
            float4 v;
            v.x = (a.x - b.x) * (a.x - b.x);
            v.y = (a.y - b.y) * (a.y - b.y);
            v.z = (a.z - b.z) * (a.z - b.z);
            v.w = (a.w - b.w) * (a.w - b.w);
            return v;
        } else {
            float4 v = sv[r * 128 + vc];
            v.x = fmaf(v.x, scale, -off);
            v.y = fmaf(v.y, scale, -off);
            v.z = fmaf(v.z, scale, -off);
            v.w = fmaf(v.w, scale, -off);
            return v;
        }
    };
    auto ld1 = [&](int r, int pcol) -> float {
        if (FIRST) {
            float d = xg[base + r * WW + pcol] - yg[base + r * WW + pcol];
            return d * d;
        } else {
            return fmaf(src[base + r * WW + pcol], scale, -off);
        }
    };

    const float4 z4 = make_float4(0.f, 0.f, 0.f, 0.f);
    float4 pm1 = (ys > 0) ? ld4(ys - 1) : z4;
    float4 p0 = ld4(ys);

    float tmin = __uint_as_float(0x7f800000u);
    float tmax = 0.0f;
    float tsum = 0.0f;
    float4* dv = (float4*)(dst + base);

    #pragma unroll
    for (int i = 0; i < RSTRIP; ++i) {
        const int y = ys + i;
        float4 p1 = (y + 1 < HH) ? ld4(y + 1) : z4;

        float lf = __shfl_up(p0.w, 1);
        float rt = __shfl_down(p0.x, 1);
        if (lane == 0)  lf = (vc > 0)   ? ld1(y, vc * 4 - 1) : 0.0f;
        if (lane == 63) rt = (vc < 127) ? ld1(y, vc * 4 + 4) : 0.0f;

        float4 e;
        e.x = 0.2f * (pm1.x + p1.x + lf   + p0.x + p0.y);
        e.y = 0.2f * (pm1.y + p1.y + p0.x + p0.y + p0.z);
        e.z = 0.2f * (pm1.z + p1.z + p0.y + p0.z + p0.w);
        e.w = 0.2f * (pm1.w + p1.w + p0.z + p0.w + rt);
        e.x = fmaxf(e.x - 0.5f, 0.0f);
        e.y = fmaxf(e.y - 0.5f, 0.0f);
        e.z = fmaxf(e.z - 0.5f, 0.0f);
        e.w = fmaxf(e.w - 0.5f, 0.0f);

        if (STORE) dv[y * 128 + vc] = e;

        tmin = fminf(tmin, fminf(fminf(e.x, e.y), fminf(e.z, e.w)));
        tmax = fmaxf(tmax, fmaxf(fmaxf(e.x, e.y), fmaxf(e.z, e.w)));
        tsum += (e.x + e.y) + (e.z + e.w);

        pm1 = p0;
        p0 = p1;
    }

    double dsum = (double)tsum;
    #pragma unroll
    for (int o2 = 32; o2 > 0; o2 >>= 1) {
        tmin = fminf(tmin, __shfl_down(tmin, o2));
        tmax = fmaxf(tmax, __shfl_down(tmax, o2));
        dsum += __shfl_down(dsum, o2);
    }

    if (lane == 0) {
        const int idx = img * WPI + blk * 4 + w;
        pmm[idx] = make_float2(tmin, tmax);
        psum[idx] = dsum;
    }
}

// ---------------------------------------------------------------------------
// kfin1: one block (64 threads) per image. For each step k: butterfly-reduce
// the 128 partials (min/max f32, sum f64), apply sum-of-normalized =
// (S - N*mn)/ptp (or S if ptp==0), weight by (k+1)^2. Store per-image f64.
// ---------------------------------------------------------------------------
__global__ __launch_bounds__(64) void kfin1(const float2* __restrict__ pmm,
                                            const double* __restrict__ psum,
                                            double* __restrict__ perImg) {
    const int img = blockIdx.x;
    const int lane = threadIdx.x;
    double tot = 0.0;
    for (int k = 0; k < STEPS; ++k) {
        const int o = (k * IMGS + img) * WPI;
        float2 a = pmm[o + lane];
        float2 b = pmm[o + 64 + lane];
        double s = psum[o + lane] + psum[o + 64 + lane];
        float tmn = fminf(a.x, b.x);
        float tmx = fmaxf(a.y, b.y);
        #pragma unroll
        for (int o2 = 32; o2 > 0; o2 >>= 1) {
            tmn = fminf(tmn, __shfl_xor(tmn, o2));
            tmx = fmaxf(tmx, __shfl_xor(tmx, o2));
            s += __shfl_xor(s, o2);
        }
        float ptp = tmx - tmn;
        double sn = (ptp > 0.0f)
                        ? (s - (double)NPIX * (double)tmn) / (double)ptp
                        : s;
        tot += sn * (double)((k + 1) * (k + 1));
    }
    if (lane == 0) perImg[img] = tot;
}

// ---------------------------------------------------------------------------
// kfin2: sum 64 per-image doubles, divide, write scalar.
// ---------------------------------------------------------------------------
__global__ void kfin2(const double* __restrict__ perImg,
                      float* __restrict__ out) {
    double v = perImg[threadIdx.x];
    #pragma unroll
    for (int o2 = 32; o2 > 0; o2 >>= 1) v += __shfl_down(v, o2);
    if (threadIdx.x == 0)
        out[0] = (float)(v / ((double)IMGS * (double)NPIX));
}

// ---------------------------------------------------------------------------
extern "C" void kernel_launch(void* const* d_in, const int* in_sizes, int n_in,
                              void* d_out, int out_size, void* d_ws, size_t ws_size,
                              hipStream_t stream) {
    const float* x = (const float*)d_in[0];
    const float* y = (const float*)d_in[1];
    float* out = (float*)d_out;

    char* ws = (char*)d_ws;
    const size_t bufBytes = (size_t)IMGS * NPIX * sizeof(float);  // 64 MiB
    float* bufA = (float*)ws;
    float* bufB = (float*)(ws + bufBytes);
    char* p = ws + 2 * bufBytes;
    float2* pmm = (float2*)p;        p += (size_t)STEPS * IMGS * WPI * sizeof(float2);
    double* psum = (double*)p;       p += (size_t)STEPS * IMGS * WPI * sizeof(double);
    double* perImg = (double*)p;

    // step 0: sources x,y directly
    kconv<1, 1><<<NBLK, 256, 0, stream>>>(x, y, nullptr, bufA, nullptr,
                                          pmm, psum);
    float* cur = bufA;
    float* nxt = bufB;
    for (int k = 1; k < STEPS - 1; ++k) {
        kconv<0, 1><<<NBLK, 256, 0, stream>>>(
            nullptr, nullptr, cur, nxt,
            pmm + (size_t)(k - 1) * IMGS * WPI,
            pmm + (size_t)k * IMGS * WPI,
            psum + (size_t)k * IMGS * WPI);
        float* tmp = cur; cur = nxt; nxt = tmp;
    }
    // last step: stats only, no field write
    kconv<0, 0><<<NBLK, 256, 0, stream>>>(
        nullptr, nullptr, cur, nullptr,
        pmm + (size_t)(STEPS - 2) * IMGS * WPI,
        pmm + (size_t)(STEPS - 1) * IMGS * WPI,
        psum + (size_t)(STEPS - 1) * IMGS * WPI);

    kfin1<<<IMGS, 64, 0, stream>>>(pmm, psum, perImg);
    kfin2<<<1, 64, 0, stream>>>(perImg, out);
}

// Round 12
// 217.768 us; speedup vs baseline: 7.9528x; 1.1554x over previous
//
#include <hip/hip_runtime.h>

#define IMGS 64
#define HH 512
#define WW 512
#define NPIX (HH * WW)          // 262144 pixels per image
#define STEPS 10
#define RSTRIP 16               // rows per wave strip (halo 18/16 = 1.125x)
#define BLKS_PER_IMG 32         // 512 / 16
#define NBLK (IMGS * BLKS_PER_IMG)   // 2048 blocks, 128 threads each
#define WPI 64                  // partials per image per step (32 blk * 2 waves)

// ---------------------------------------------------------------------------
// kconv<FIRST,STORE>: one erosion step, register sliding-window stencil.
//   Block = 128 threads = 2 waves; wave h owns half-row cols [h*256,h*256+256)
//   x 16 rows, sliding pm1/p0/p1 through registers (each row fetched once per
//   strip; halo = 2 rows per 16).
//   Prev-step stats FUSED at block start: one 64-lane butterfly over the 64
//   float2 partials of step k-1 (512 B broadcast, L2-hit) -> scale/off.
//   FIRST: source = (x-y)^2 on the fly; else prev ero normalized on the fly
//   (per-image affine; OOB taps exact 0 = zero-pad of the normalized field).
//   dil = 0.2*(C+N+S+E+W); ero = max(dil-0.5,0). STORE=0 on the last step
//   skips the 64 MB field write. Per-wave min/max(f32)+sum(f64) partials,
//   plain stores; no LDS, no barriers, no atomics.
//   XCD swizzle: contiguous work chunks per XCD for halo L2 locality.
// ---------------------------------------------------------------------------
template <int FIRST, int STORE>
__global__ __launch_bounds__(128) void kconv(const float* __restrict__ xg,
                                             const float* __restrict__ yg,
                                             const float* __restrict__ src,
                                             float* __restrict__ dst,
                                             const float2* __restrict__ prevMM,
                                             float2* __restrict__ pmm,
                                             double* __restrict__ psum) {
    const int bid = blockIdx.x;
    const int swz = (bid & 7) * (NBLK / 8) + (bid >> 3);  // XCD-contiguous
    const int img = swz >> 5;             // 32 blocks per image
    const int blk = swz & 31;
    const int tid = threadIdx.x;
    const int w = tid >> 6;               // wave = half-row select
    const int lane = tid & 63;
    const int vc = w * 64 + lane;         // vec4 column [0,128)
    const int ys = blk * RSTRIP;
    const size_t base = (size_t)img * NPIX;

    float scale = 1.0f, off = 0.0f;
    if (!FIRST) {
        float2 a = prevMM[img * WPI + lane];
        float tmn = a.x, tmx = a.y;
        #pragma unroll
        for (int o2 = 32; o2 > 0; o2 >>= 1) {
            tmn = fminf(tmn, __shfl_xor(tmn, o2));
            tmx = fmaxf(tmx, __shfl_xor(tmx, o2));
        }
        float ptp = tmx - tmn;
        if (ptp > 0.0f) { scale = 1.0f / ptp; off = tmn * scale; }
    }

    const float4* xv = (const float4*)(xg + base);
    const float4* yv = (const float4*)(yg + base);
    const float4* sv = (const float4*)(src + base);

    auto ld4 = [&](int r) -> float4 {     // row r, this thread's vec4 column
        if (FIRST) {
            float4 a = xv[r * 128 + vc];
            float4 b = yv[r * 128 + vc];
            float4 v;
            v.x = (a.x - b.x) * (a.x - b.x);
            v.y = (a.y - b.y) * (a.y - b.y);
            v.z = (a.z - b.z) * (a.z - b.z);
            v.w = (a.w - b.w) * (a.w - b.w);
            return v;
        } else {
            float4 v = sv[r * 128 + vc];
            v.x = fmaf(v.x, scale, -off);
            v.y = fmaf(v.y, scale, -off);
            v.z = fmaf(v.z, scale, -off);
            v.w = fmaf(v.w, scale, -off);
            return v;
        }
    };
    auto ld1 = [&](int r, int pcol) -> float {
        if (FIRST) {
            float d = xg[base + r * WW + pcol] - yg[base + r * WW + pcol];
            return d * d;
        } else {
            return fmaf(src[base + r * WW + pcol], scale, -off);
        }
    };

    const float4 z4 = make_float4(0.f, 0.f, 0.f, 0.f);
    float4 pm1 = (ys > 0) ? ld4(ys - 1) : z4;
    float4 p0 = ld4(ys);

    float tmin = __uint_as_float(0x7f800000u);
    float tmax = 0.0f;
    float tsum = 0.0f;
    float4* dv = (float4*)(dst + base);

    #pragma unroll
    for (int i = 0; i < RSTRIP; ++i) {
        const int y = ys + i;
        float4 p1 = (y + 1 < HH) ? ld4(y + 1) : z4;

        float lf = __shfl_up(p0.w, 1);
        float rt = __shfl_down(p0.x, 1);
        if (lane == 0)  lf = (vc > 0)   ? ld1(y, vc * 4 - 1) : 0.0f;
        if (lane == 63) rt = (vc < 127) ? ld1(y, vc * 4 + 4) : 0.0f;

        float4 e;
        e.x = 0.2f * (pm1.x + p1.x + lf   + p0.x + p0.y);
        e.y = 0.2f * (pm1.y + p1.y + p0.x + p0.y + p0.z);
        e.z = 0.2f * (pm1.z + p1.z + p0.y + p0.z + p0.w);
        e.w = 0.2f * (pm1.w + p1.w + p0.z + p0.w + rt);
        e.x = fmaxf(e.x - 0.5f, 0.0f);
        e.y = fmaxf(e.y - 0.5f, 0.0f);
        e.z = fmaxf(e.z - 0.5f, 0.0f);
        e.w = fmaxf(e.w - 0.5f, 0.0f);

        if (STORE) dv[y * 128 + vc] = e;

        tmin = fminf(tmin, fminf(fminf(e.x, e.y), fminf(e.z, e.w)));
        tmax = fmaxf(tmax, fmaxf(fmaxf(e.x, e.y), fmaxf(e.z, e.w)));
        tsum += (e.x + e.y) + (e.z + e.w);

        pm1 = p0;
        p0 = p1;
    }

    double dsum = (double)tsum;
    #pragma unroll
    for (int o2 = 32; o2 > 0; o2 >>= 1) {
        tmin = fminf(tmin, __shfl_down(tmin, o2));
        tmax = fmaxf(tmax, __shfl_down(tmax, o2));
        dsum += __shfl_down(dsum, o2);
    }

    if (lane == 0) {
        const int idx = img * WPI + blk * 2 + w;
        pmm[idx] = make_float2(tmin, tmax);
        psum[idx] = dsum;
    }
}

// ---------------------------------------------------------------------------
// kfin1: one block (64 threads) per image. For each step k: butterfly-reduce
// the 64 partials (min/max f32, sum f64), apply sum-of-normalized =
// (S - N*mn)/ptp (or S if ptp==0), weight by (k+1)^2. Store per-image f64.
// ---------------------------------------------------------------------------
__global__ __launch_bounds__(64) void kfin1(const float2* __restrict__ pmm,
                                            const double* __restrict__ psum,
                                            double* __restrict__ perImg) {
    const int img = blockIdx.x;
    const int lane = threadIdx.x;
    double tot = 0.0;
    for (int k = 0; k < STEPS; ++k) {
        const int o = (k * IMGS + img) * WPI;
        float2 a = pmm[o + lane];
        double s = psum[o + lane];
        float tmn = a.x;
        float tmx = a.y;
        #pragma unroll
        for (int o2 = 32; o2 > 0; o2 >>= 1) {
            tmn = fminf(tmn, __shfl_xor(tmn, o2));
            tmx = fmaxf(tmx, __shfl_xor(tmx, o2));
            s += __shfl_xor(s, o2);
        }
        float ptp = tmx - tmn;
        double sn = (ptp > 0.0f)
                        ? (s - (double)NPIX * (double)tmn) / (double)ptp
                        : s;
        tot += sn * (double)((k + 1) * (k + 1));
    }
    if (lane == 0) perImg[img] = tot;
}

// ---------------------------------------------------------------------------
// kfin2: sum 64 per-image doubles, divide, write scalar.
// ---------------------------------------------------------------------------
__global__ void kfin2(const double* __restrict__ perImg,
                      float* __restrict__ out) {
    double v = perImg[threadIdx.x];
    #pragma unroll
    for (int o2 = 32; o2 > 0; o2 >>= 1) v += __shfl_down(v, o2);
    if (threadIdx.x == 0)
        out[0] = (float)(v / ((double)IMGS * (double)NPIX));
}

// ---------------------------------------------------------------------------
extern "C" void kernel_launch(void* const* d_in, const int* in_sizes, int n_in,
                              void* d_out, int out_size, void* d_ws, size_t ws_size,
                              hipStream_t stream) {
    const float* x = (const float*)d_in[0];
    const float* y = (const float*)d_in[1];
    float* out = (float*)d_out;

    char* ws = (char*)d_ws;
    const size_t bufBytes = (size_t)IMGS * NPIX * sizeof(float);  // 64 MiB
    float* bufA = (float*)ws;
    float* bufB = (float*)(ws + bufBytes);
    char* p = ws + 2 * bufBytes;
    float2* pmm = (float2*)p;        p += (size_t)STEPS * IMGS * WPI * sizeof(float2);
    double* psum = (double*)p;       p += (size_t)STEPS * IMGS * WPI * sizeof(double);
    double* perImg = (double*)p;

    // step 0: sources x,y directly
    kconv<1, 1><<<NBLK, 128, 0, stream>>>(x, y, nullptr, bufA, nullptr,
                                          pmm, psum);
    float* cur = bufA;
    float* nxt = bufB;
    for (int k = 1; k < STEPS - 1; ++k) {
        kconv<0, 1><<<NBLK, 128, 0, stream>>>(
            nullptr, nullptr, cur, nxt,
            pmm + (size_t)(k - 1) * IMGS * WPI,
            pmm + (size_t)k * IMGS * WPI,
            psum + (size_t)k * IMGS * WPI);
        float* tmp = cur; cur = nxt; nxt = tmp;
    }
    // last step: stats only, no field write
    kconv<0, 0><<<NBLK, 128, 0, stream>>>(
        nullptr, nullptr, cur, nullptr,
        pmm + (size_t)(STEPS - 2) * IMGS * WPI,
        pmm + (size_t)(STEPS - 1) * IMGS * WPI,
        psum + (size_t)(STEPS - 1) * IMGS * WPI);

    kfin1<<<IMGS, 64, 0, stream>>>(pmm, psum, perImg);
    kfin2<<<1, 64, 0, stream>>>(perImg, out);
}